// Round 21
// baseline (54.765 us; speedup 1.0000x reference)
//
#include <hip/hip_runtime.h>
#include <math.h>

#define NBATCH 128
#define NP 256
#define NC 64
#define KNN 16
#define EPSV 1e-3f

typedef __bf16 bf16_t;
typedef bf16_t bf16x8 __attribute__((ext_vector_type(8)));
typedef float f32x4 __attribute__((ext_vector_type(4)));
typedef unsigned short u16x4 __attribute__((ext_vector_type(4)));

static __device__ __forceinline__ f32x4 mfma16(bf16x8 a, bf16x8 b, f32x4 c) {
    return __builtin_amdgcn_mfma_f32_16x16x32_bf16(a, b, c, 0, 0, 0);
}
static __device__ __forceinline__ unsigned short f2bfu(float f) {
    union { bf16_t b; unsigned short u; } cv; cv.b = (bf16_t)f; return cv.u;
}
static __device__ __forceinline__ float bfu2f(unsigned short u) {
    unsigned x = ((unsigned)u) << 16;
    return __int_as_float((int)x);
}
static __device__ __forceinline__ unsigned umin2(unsigned a, unsigned b) { return a < b ? a : b; }
static __device__ __forceinline__ unsigned umax2(unsigned a, unsigned b) { return a > b ? a : b; }

static __device__ __forceinline__ bf16x8 pack8(float4 a, float4 b) {
    bf16x8 r;
    r[0] = (bf16_t)a.x; r[1] = (bf16_t)a.y; r[2] = (bf16_t)a.z; r[3] = (bf16_t)a.w;
    r[4] = (bf16_t)b.x; r[5] = (bf16_t)b.y; r[6] = (bf16_t)b.z; r[7] = (bf16_t)b.w;
    return r;
}
// relu'd f32x4 pair -> bf16x8 (j = (t&1)*4 + r ordering)
static __device__ __forceinline__ bf16x8 packrelu(f32x4 a, f32x4 b) {
    bf16x8 r;
    r[0] = (bf16_t)fmaxf(a[0], 0.f); r[1] = (bf16_t)fmaxf(a[1], 0.f);
    r[2] = (bf16_t)fmaxf(a[2], 0.f); r[3] = (bf16_t)fmaxf(a[3], 0.f);
    r[4] = (bf16_t)fmaxf(b[0], 0.f); r[5] = (bf16_t)fmaxf(b[1], 0.f);
    r[6] = (bf16_t)fmaxf(b[2], 0.f); r[7] = (bf16_t)fmaxf(b[3], 0.f);
    return r;
}

// 16-lane (i-group) sum via DPP butterfly — VALU only, no DS pipe.
template <int CTRL>
static __device__ __forceinline__ float dppadd(float v) {
    int x = __builtin_amdgcn_mov_dpp(__float_as_int(v), CTRL, 0xF, 0xF, true);
    return v + __int_as_float(x);
}
static __device__ __forceinline__ float sum16(float v) {
    v = dppadd<0xB1>(v);    // quad_perm [1,0,3,2]
    v = dppadd<0x4E>(v);    // quad_perm [2,3,0,1]
    v = dppadd<0x141>(v);   // row_half_mirror
    v = dppadd<0x140>(v);   // row_mirror
    return v;
}

// Compiler-only ordering fence (R11-validated; wave-private LDS, in-order DS).
#define CFENCE() asm volatile("" ::: "memory")

// Sorted-ascending insert, med3 form (2 ops/level).
#define INSERTK(k_)                                                   \
    do {                                                              \
        _Pragma("unroll")                                             \
        for (int ii = KNN - 1; ii >= 1; --ii)                         \
            bk[ii] = umin2(umax2((k_), bk[ii - 1]), bk[ii]);          \
        bk[0] = umin2((k_), bk[0]);                                   \
    } while (0)

// ---------------------------------------------------------------------------
// prep_kernel (verbatim R17 prep; 82 blocks). Swapped-operand A-frags +
// folded BN. wsf: V|w0hi|scl1*w1|scl2*w2|ws (8 frags each).
// bnp: shf'[3][64] pos | scl3/16 [192,256) | sscl [256,320) | sshf [320,384).
// ---------------------------------------------------------------------------
__global__ __launch_bounds__(256) void prep_kernel(
    const float* __restrict__ w0, const float* __restrict__ w1,
    const float* __restrict__ w2, const float* __restrict__ sc_w,
    const float* __restrict__ gammas, const float* __restrict__ betas,
    const float* __restrict__ means, const float* __restrict__ variances,
    const float* __restrict__ sc_gamma, const float* __restrict__ sc_beta,
    const float* __restrict__ sc_mean, const float* __restrict__ sc_var,
    unsigned short* __restrict__ wsf, float* __restrict__ bnp)
{
    const int tid = blockIdx.x * 256 + threadIdx.x;
    if (tid < 20480) {
        const int region = tid >> 12;          // 0:V 1:w0hi 2:w1' 3:w2' 4:ws
        const int e2 = tid & 4095;
        const int f = e2 >> 9;
        const int r = e2 & 511;
        const int lane = r >> 3, j = r & 7;
        const int ks = f >> 2, t = f & 3;
        const int m = lane & 15;
        const int k_in = ks * 32 + (lane >> 4) * 8 + j;
        const int kp = (t >> 1) * 32 + (m >> 2) * 8 + (t & 1) * 4 + (m & 3);
        float v;
        if (region == 0)      v = w0[k_in * 64 + kp] - w0[(64 + k_in) * 64 + kp];
        else if (region == 1) v = w0[(64 + k_in) * 64 + kp];
        else if (region == 2) {
            float s1 = gammas[k_in] * rsqrtf(variances[k_in] + EPSV);
            v = s1 * w1[k_in * 64 + kp];
        } else if (region == 3) {
            float s2 = gammas[64 + k_in] * rsqrtf(variances[64 + k_in] + EPSV);
            v = s2 * w2[k_in * 64 + kp];
        } else {
            v = sc_w[k_in * 64 + (4 * m + t)];
        }
        wsf[tid] = f2bfu(v);
    } else {
        const int e = tid - 20480;
        if (e < 192) {
            const int L = e >> 6;
            const int pos = e & 63;
            const int t = pos >> 4, m = pos & 15;
            const int c = (t >> 1) * 32 + (m >> 2) * 8 + (t & 1) * 4 + (m & 3);
            float scl = gammas[L * 64 + c] * rsqrtf(variances[L * 64 + c] + EPSV);
            float shf = betas[L * 64 + c] - means[L * 64 + c] * scl;
            bnp[e] = shf / scl;
        } else if (e < 256) {
            const int c = e - 192;
            float s3 = gammas[128 + c] * rsqrtf(variances[128 + c] + EPSV);
            bnp[e] = s3 * (1.f / 16.f);
        } else if (e < 320) {
            const int c = e - 256;
            bnp[e] = sc_gamma[c] * rsqrtf(sc_var[c] + EPSV);
        } else if (e < 384) {
            const int c = e - 320;
            float s = sc_gamma[c] * rsqrtf(sc_var[c] + EPSV);
            bnp[e] = sc_beta[c] - sc_mean[c] * s;
        }
    }
}

// ---------------------------------------------------------------------------
// knedge_kernel: fused knn+edge, 1024 blocks x 32 queries (4 blocks/CU,
// ~12 waves/CU vs R20's 4). Features read f32 from global (L2-resident per
// XCD via swizzle; inline cvt). knn: 8-way candidate split + 3-level tree
// merge. edge: R17/R20-verified register-chained body, 1 seg.
// LDS ~26 KB: sp 4K | mrg 8.7K | nkbuf 1K | s0 8K | fts 4K | cin 0.5K.
// ---------------------------------------------------------------------------
__global__ __launch_bounds__(256) void knedge_kernel(
    const float* __restrict__ points, const float* __restrict__ features,
    const unsigned short* __restrict__ wsf, const float* __restrict__ bnp,
    float* __restrict__ out)
{
    __shared__ __align__(16) float4 sp[NP];                     // 4 KB
    __shared__ unsigned mrg[32][4][17];                         // 8.7 KB
    __shared__ unsigned short nkbuf[32][16];                    // 1 KB
    __shared__ __align__(16) float s0buf[4][8][64];             // 8 KB
    __shared__ __align__(16) unsigned short ftsbuf[4][8][64];   // 4 KB
    __shared__ __align__(16) float cinlds[128];                 // 0.5 KB

    // XCD swizzle: 1024 blocks = 8 XCDs x 128; batch (8 blocks) stays on one XCD
    const int kb = (blockIdx.x & 7) * 128 + (blockIdx.x >> 3);
    const int bb = kb >> 3;
    const int q0 = (kb & 7) * 32;
    const int t = threadIdx.x;

    // ---- phase A1: points -> sp; bias table -> cinlds ----
    {
        const float* pb = points + (size_t)bb * NP * 3;
        sp[t] = make_float4(pb[t * 3 + 0], pb[t * 3 + 1], pb[t * 3 + 2], 0.f);
        if (t < 128) cinlds[t] = bnp[64 + t];   // shf2'[64], shf3'[64]
    }
    __syncthreads();

    // ---- phase A2: knn, 8-way split (q = t&31, oct = t>>5, 32 cands each) --
    {
        const int q = t & 31;
        const int oct = t >> 5;
        const int p = q0 + q;
        const float4 qp = sp[p];
        unsigned bk[KNN];
#pragma unroll
        for (int ii = 0; ii < KNN; ++ii) bk[ii] = 0xFFFFFFFFu;
        const int cbase = oct * 32;
#pragma unroll 4
        for (int c = 0; c < 32; ++c) {
            const int cand = cbase + c;
            const float4 P = sp[cand];
            const float dx = qp.x - P.x, dy = qp.y - P.y, dz = qp.z - P.z;
            const float d = fmaf(dx, dx, fmaf(dy, dy, dz * dz));
            unsigned key = (__float_as_uint(d) & 0xFFFFFF00u) | (unsigned)cand;
            key = (cand == p) ? 0xFFFFFFFFu : key;
            INSERTK(key);
        }
        // tree merge: L1 {0<-1, 2<-3, 4<-5, 6<-7}
        if (oct & 1) {
#pragma unroll
            for (int ii = 0; ii < KNN; ++ii) mrg[q][oct >> 1][ii] = bk[ii];
        }
        __syncthreads();
        if (!(oct & 1)) {
            const unsigned* src = mrg[q][oct >> 1];
            for (int j = 0; j < KNN; ++j) {
                const unsigned key = src[j];
                if (key >= bk[KNN - 1]) break;
                INSERTK(key);
            }
        }
        __syncthreads();
        // L2 {0<-2, 4<-6}: oct2 -> slot0, oct6 -> slot1
        if (oct == 2 || oct == 6) {
#pragma unroll
            for (int ii = 0; ii < KNN; ++ii) mrg[q][oct >> 2][ii] = bk[ii];
        }
        __syncthreads();
        if (oct == 0 || oct == 4) {
            const unsigned* src = mrg[q][oct >> 2];
            for (int j = 0; j < KNN; ++j) {
                const unsigned key = src[j];
                if (key >= bk[KNN - 1]) break;
                INSERTK(key);
            }
        }
        __syncthreads();
        // L3 {0<-4}
        if (oct == 4) {
#pragma unroll
            for (int ii = 0; ii < KNN; ++ii) mrg[q][0][ii] = bk[ii];
        }
        __syncthreads();
        if (oct == 0) {
            const unsigned* src = mrg[q][0];
            for (int j = 0; j < KNN; ++j) {
                const unsigned key = src[j];
                if (key >= bk[KNN - 1]) break;
                INSERTK(key);
            }
#pragma unroll
            for (int ii = 0; ii < KNN; ++ii)
                nkbuf[q][ii] = (unsigned short)(bk[ii] & 0xFFu);
        }
    }
    __syncthreads();

    // ---- phase B: edge MLP (register-chained, verified body; 1 seg) ----
    const int wid = t >> 6;
    const int l = t & 63;
    const int i = l & 15;
    const int h = l >> 4;
    const int prel = q0 + wid * 8;              // wave's 8 points (batch-rel)

    // weight A-frags resident in registers (24 frags = 96 VGPR)
    bf16x8 wr[24];
    {
        const bf16x8* __restrict__ W = (const bf16x8*)(wsf + 4096);
#pragma unroll
        for (int f = 0; f < 24; ++f) wr[f] = W[f * 64 + l];
    }
    const bf16x8* __restrict__ WV = (const bf16x8*)(wsf);
    const bf16x8* __restrict__ WS = (const bf16x8*)(wsf + 16384);
    const float* __restrict__ fbat = features + (size_t)bb * NP * NC;

    // center rows, loaded f32 + packed once; reused by s0 (B-op) and
    // shortcut (A-op) — byte-identical fragments.
    bf16x8 a0, a1;
    {
        const float* cp = fbat + (size_t)(prel + (i & 7)) * NC;
        float4 c0 = *(const float4*)(cp + 8 * h);
        float4 c1 = *(const float4*)(cp + 8 * h + 4);
        float4 c2 = *(const float4*)(cp + 32 + 8 * h);
        float4 c3 = *(const float4*)(cp + 32 + 8 * h + 4);
        a0 = pack8(c0, c1);
        a1 = pack8(c2, c3);
    }

    // ---- s0 prologue: s0 = shf1' + ctr @ V ----
#pragma unroll
    for (int tq = 0; tq < 4; ++tq) {
        f32x4 acc = *(const f32x4*)&bnp[tq * 16 + 4 * h];   // shf1'
        acc = mfma16(WV[tq * 64 + l], a0, acc);
        acc = mfma16(WV[(4 + tq) * 64 + l], a1, acc);
        if (i < 8)
            *(f32x4*)&s0buf[wid][i][tq * 16 + 4 * h] = acc;
    }
    int nks[8];
#pragma unroll
    for (int q = 0; q < 8; ++q) nks[q] = nkbuf[wid * 8 + q][i];
    CFENCE();   // s0buf writes before main-loop reads (wave-private)

    // prime point 0's neighbor B-fragments (lane i -> neighbor i)
    bf16x8 fb0, fb1;
    {
        const float* np_ = fbat + (size_t)nks[0] * NC;
        float4 n0 = *(const float4*)(np_ + 8 * h);
        float4 n1 = *(const float4*)(np_ + 8 * h + 4);
        float4 n2 = *(const float4*)(np_ + 32 + 8 * h);
        float4 n3 = *(const float4*)(np_ + 32 + 8 * h + 4);
        fb0 = pack8(n0, n1);
        fb1 = pack8(n2, n3);
    }

#pragma unroll
    for (int q = 0; q < 8; ++q) {
        f32x4 acc[4];
        // ---- L1 ----
#pragma unroll
        for (int tq = 0; tq < 4; ++tq) {
            f32x4 z = *(const f32x4*)&s0buf[wid][q][tq * 16 + 4 * h];
            z = mfma16(wr[tq], fb0, z);
            acc[tq] = mfma16(wr[4 + tq], fb1, z);
        }
        // prefetch + pack next point's neighbor fragments
        bf16x8 g0, g1;
        if (q < 7) {
            const float* np_ = fbat + (size_t)nks[q + 1] * NC;
            float4 n0 = *(const float4*)(np_ + 8 * h);
            float4 n1 = *(const float4*)(np_ + 8 * h + 4);
            float4 n2 = *(const float4*)(np_ + 32 + 8 * h);
            float4 n3 = *(const float4*)(np_ + 32 + 8 * h + 4);
            g0 = pack8(n0, n1);
            g1 = pack8(n2, n3);
        }
        bf16x8 x0 = packrelu(acc[0], acc[1]);
        bf16x8 x1 = packrelu(acc[2], acc[3]);
        // ---- L2 ----
#pragma unroll
        for (int tq = 0; tq < 4; ++tq) {
            f32x4 z = mfma16(wr[8 + tq], x0, *(const f32x4*)&cinlds[tq * 16 + 4 * h]);
            acc[tq] = mfma16(wr[12 + tq], x1, z);
        }
        bf16x8 y0 = packrelu(acc[0], acc[1]);
        bf16x8 y1 = packrelu(acc[2], acc[3]);
        // ---- L3 ----
#pragma unroll
        for (int tq = 0; tq < 4; ++tq) {
            f32x4 z = mfma16(wr[16 + tq], y0, *(const f32x4*)&cinlds[64 + tq * 16 + 4 * h]);
            acc[tq] = mfma16(wr[20 + tq], y1, z);
        }
        // relu + k-mean via DPP butterfly
        float st[4][4];
#pragma unroll
        for (int tq = 0; tq < 4; ++tq)
#pragma unroll
            for (int r = 0; r < 4; ++r)
                st[tq][r] = sum16(fmaxf(acc[tq][r], 0.f));
        if (i == 0) {
#pragma unroll
            for (int tq = 0; tq < 4; ++tq) {
                u16x4 pk;
#pragma unroll
                for (int r = 0; r < 4; ++r) pk[r] = f2bfu(st[tq][r]);
                *(u16x4*)&ftsbuf[wid][q][(tq >> 1) * 32 + h * 8 + (tq & 1) * 4] = pk;
            }
        }
        fb0 = g0; fb1 = g1;
    }
    CFENCE();  // ftsbuf writes before epilogue reads (same wave)

    // ---- shortcut GEMM + epilogue ----
    {
        const int i4 = 4 * i;
        float4 sscl = *(const float4*)&bnp[256 + i4];
        float4 sshf = *(const float4*)&bnp[320 + i4];
        float4 f3q  = *(const float4*)&bnp[192 + i4];   // scl3/16
        f32x4 acc[4];
#pragma unroll
        for (int tq = 0; tq < 4; ++tq) {
            f32x4 z = {0.f, 0.f, 0.f, 0.f};
            z = mfma16(a0, WS[tq * 64 + l], z);
            acc[tq] = mfma16(a1, WS[(4 + tq) * 64 + l], z);
        }
        if (h < 2) {
            const float* ss_ = (const float*)&sscl;
            const float* sf_ = (const float*)&sshf;
            const float* f3_ = (const float*)&f3q;
#pragma unroll
            for (int r = 0; r < 4; ++r) {
                const int q = h * 4 + r;
                u16x4 ftsu = *(const u16x4*)&ftsbuf[wid][q][i4];
                float4 o;
                float* o_ = (float*)&o;
#pragma unroll
                for (int tq = 0; tq < 4; ++tq)
                    o_[tq] = fmaxf(fmaf(acc[tq][r], ss_[tq], sf_[tq]) + bfu2f(ftsu[tq]) * f3_[tq], 0.f);
                *(float4*)&out[(size_t)(bb * NP + prel + q) * NC + i4] = o;
            }
        }
    }
}

extern "C" void kernel_launch(void* const* d_in, const int* in_sizes, int n_in,
                              void* d_out, int out_size, void* d_ws, size_t ws_size,
                              hipStream_t stream) {
    const float* points    = (const float*)d_in[0];
    const float* features  = (const float*)d_in[1];
    const float* w0        = (const float*)d_in[2];
    const float* w1        = (const float*)d_in[3];
    const float* w2        = (const float*)d_in[4];
    const float* gammas    = (const float*)d_in[5];
    const float* betas     = (const float*)d_in[6];
    const float* means     = (const float*)d_in[7];
    const float* variances = (const float*)d_in[8];
    const float* sc_w      = (const float*)d_in[9];
    const float* sc_gamma  = (const float*)d_in[10];
    const float* sc_beta   = (const float*)d_in[11];
    const float* sc_mean   = (const float*)d_in[12];
    const float* sc_var    = (const float*)d_in[13];
    float* out = (float*)d_out;

    unsigned short* wsf = (unsigned short*)d_ws;                 // 40 KB
    float* bnp = (float*)((char*)d_ws + 40960);                  // 1.5 KB

    prep_kernel<<<82, 256, 0, stream>>>(w0, w1, w2, sc_w, gammas, betas, means,
                                        variances, sc_gamma, sc_beta, sc_mean,
                                        sc_var, wsf, bnp);
    knedge_kernel<<<NBATCH * 8, 256, 0, stream>>>(points, features, wsf, bnp, out);
}

// Round 22
// 48.025 us; speedup vs baseline: 1.1403x; 1.1403x over previous
//
#include <hip/hip_runtime.h>
#include <math.h>

#define NBATCH 128
#define NP 256
#define NC 64
#define KNN 16
#define EPSV 1e-3f

typedef __bf16 bf16_t;
typedef bf16_t bf16x8 __attribute__((ext_vector_type(8)));
typedef float f32x4 __attribute__((ext_vector_type(4)));

static __device__ __forceinline__ f32x4 mfma16(bf16x8 a, bf16x8 b, f32x4 c) {
    return __builtin_amdgcn_mfma_f32_16x16x32_bf16(a, b, c, 0, 0, 0);
}
static __device__ __forceinline__ unsigned short f2bfu(float f) {
    union { bf16_t b; unsigned short u; } cv; cv.b = (bf16_t)f; return cv.u;
}
static __device__ __forceinline__ unsigned umin2(unsigned a, unsigned b) { return a < b ? a : b; }
static __device__ __forceinline__ unsigned umax2(unsigned a, unsigned b) { return a > b ? a : b; }

// relu'd f32x4 pair -> bf16x8 (j = (t&1)*4 + r ordering)
static __device__ __forceinline__ bf16x8 packrelu(f32x4 a, f32x4 b) {
    bf16x8 r;
    r[0] = (bf16_t)fmaxf(a[0], 0.f); r[1] = (bf16_t)fmaxf(a[1], 0.f);
    r[2] = (bf16_t)fmaxf(a[2], 0.f); r[3] = (bf16_t)fmaxf(a[3], 0.f);
    r[4] = (bf16_t)fmaxf(b[0], 0.f); r[5] = (bf16_t)fmaxf(b[1], 0.f);
    r[6] = (bf16_t)fmaxf(b[2], 0.f); r[7] = (bf16_t)fmaxf(b[3], 0.f);
    return r;
}

// Compiler-only ordering fence (R11-validated; wave-private LDS, in-order DS).
#define CFENCE() asm volatile("" ::: "memory")

// Sorted-ascending insert, med3 form (2 ops/level).
#define INSERTK(k_)                                                   \
    do {                                                              \
        _Pragma("unroll")                                             \
        for (int ii = KNN - 1; ii >= 1; --ii)                         \
            bk[ii] = umin2(umax2((k_), bk[ii - 1]), bk[ii]);          \
        bk[0] = umin2((k_), bk[0]);                                   \
    } while (0)

// ---------------------------------------------------------------------------
// setup_kernel: fcvt [0,1024) | prep [1024,1106) | knn [1106,1362).
//
// Mixed-orientation weight layout:
//  wsf (u16, 8 frags each):
//   [0,4k)    V A-frags      (L1 center, new orient; out-cols kappa-permuted)
//   [4k,8k)   w0hi A-frags   (L1 neighbor, new orient)
//   [8k,12k)  scl1*w1 A-frags(L2, new orient)
//   [12k,16k) scl2*w2 B-frags(L3, OLD orient: rows=in-ch plain, col=t*16+m)
//   [16k,20k) sc_w B-frags   (shortcut, OLD orient: col=t*16+m)
//  bnp (f32): [0,64) shf1' kappa-pos | [64,128) shf2' kappa-pos |
//   [128,192) shf3' PLAIN ch | [192,256) scl3/16 plain |
//   [256,320) sscl plain | [320,384) sshf plain.
// ---------------------------------------------------------------------------
__global__ __launch_bounds__(256) void setup_kernel(
    const float* __restrict__ points, const float* __restrict__ features,
    const float* __restrict__ w0, const float* __restrict__ w1,
    const float* __restrict__ w2, const float* __restrict__ sc_w,
    const float* __restrict__ gammas, const float* __restrict__ betas,
    const float* __restrict__ means, const float* __restrict__ variances,
    const float* __restrict__ sc_gamma, const float* __restrict__ sc_beta,
    const float* __restrict__ sc_mean, const float* __restrict__ sc_var,
    unsigned short* __restrict__ fbf, unsigned short* __restrict__ wsf,
    float* __restrict__ bnp, int* __restrict__ knn_out)
{
    const int bid = blockIdx.x;
    if (bid < 1024) {
        // ---- fcvt ----
        const int tid = bid * 256 + threadIdx.x;
        const float4 a = ((const float4*)features)[tid * 2];
        const float4 b = ((const float4*)features)[tid * 2 + 1];
        union { unsigned short s[8]; uint4 v; } r;
        r.s[0] = f2bfu(a.x); r.s[1] = f2bfu(a.y); r.s[2] = f2bfu(a.z); r.s[3] = f2bfu(a.w);
        r.s[4] = f2bfu(b.x); r.s[5] = f2bfu(b.y); r.s[6] = f2bfu(b.z); r.s[7] = f2bfu(b.w);
        ((uint4*)fbf)[tid] = r.v;
    } else if (bid < 1106) {
        // ---- prep ----
        const int tid = (bid - 1024) * 256 + threadIdx.x;
        if (tid < 20480) {
            const int region = tid >> 12;          // 0:V 1:w0hi 2:w1' 3:w2' 4:ws
            const int e2 = tid & 4095;
            const int f = e2 >> 9;                 // frag = ks*4 + t
            const int r = e2 & 511;
            const int lane = r >> 3, j = r & 7;
            const int ks = f >> 2, t = f & 3;
            const int m = lane & 15;
            const int k_in = ks * 32 + (lane >> 4) * 8 + j;
            float v;
            if (region <= 2) {
                // A-frags (new orientation): out-col kappa-permuted
                const int kp = (t >> 1) * 32 + (m >> 2) * 8 + (t & 1) * 4 + (m & 3);
                if (region == 0)      v = w0[k_in * 64 + kp] - w0[(64 + k_in) * 64 + kp];
                else if (region == 1) v = w0[(64 + k_in) * 64 + kp];
                else {
                    float s1 = gammas[k_in] * rsqrtf(variances[k_in] + EPSV);
                    v = s1 * w1[k_in * 64 + kp];
                }
            } else {
                // B-frags (old orientation): rows plain in-ch, col plain t*16+m
                const int col = t * 16 + m;
                if (region == 3) {
                    float s2 = gammas[64 + k_in] * rsqrtf(variances[64 + k_in] + EPSV);
                    v = s2 * w2[k_in * 64 + col];
                } else {
                    v = sc_w[k_in * 64 + col];
                }
            }
            wsf[tid] = f2bfu(v);
        } else {
            const int e = tid - 20480;
            if (e < 128) {
                // shf1', shf2' in kappa-position order
                const int L = e >> 6;
                const int pos = e & 63;
                const int t = pos >> 4, m = pos & 15;
                const int c = (t >> 1) * 32 + (m >> 2) * 8 + (t & 1) * 4 + (m & 3);
                float scl = gammas[L * 64 + c] * rsqrtf(variances[L * 64 + c] + EPSV);
                float shf = betas[L * 64 + c] - means[L * 64 + c] * scl;
                bnp[e] = shf / scl;
            } else if (e < 192) {
                // shf3' PLAIN channel order
                const int c = e - 128;
                float scl = gammas[128 + c] * rsqrtf(variances[128 + c] + EPSV);
                float shf = betas[128 + c] - means[128 + c] * scl;
                bnp[e] = shf / scl;
            } else if (e < 256) {
                const int c = e - 192;
                float s3 = gammas[128 + c] * rsqrtf(variances[128 + c] + EPSV);
                bnp[e] = s3 * (1.f / 16.f);
            } else if (e < 320) {
                const int c = e - 256;
                bnp[e] = sc_gamma[c] * rsqrtf(sc_var[c] + EPSV);
            } else if (e < 384) {
                const int c = e - 320;
                float s = sc_gamma[c] * rsqrtf(sc_var[c] + EPSV);
                bnp[e] = sc_beta[c] - sc_mean[c] * s;
            }
        }
    } else {
        // ---- knn (2-way split, med3 keys) ----
        __shared__ __align__(16) float4 sp[NP];
        __shared__ unsigned sk[128][17];
        const int kb = bid - 1106;
        const int bb = kb >> 1;
        const int qbase = (kb & 1) * 128;
        const int t = threadIdx.x;
        const int qt = t & 127;
        const int half = t >> 7;
        const int p = qbase + qt;

        const float* pb = points + (size_t)bb * NP * 3;
        sp[t] = make_float4(pb[t * 3 + 0], pb[t * 3 + 1], pb[t * 3 + 2], 0.f);
        __syncthreads();

        const float4 qp = sp[p];
        unsigned bk[KNN];
#pragma unroll
        for (int i = 0; i < KNN; ++i) bk[i] = 0xFFFFFFFFu;

        const int cbase = half * 128;
#pragma unroll 4
        for (int c = 0; c < 128; ++c) {
            const int cand = cbase + c;
            const float4 P = sp[cand];
            const float dx = qp.x - P.x, dy = qp.y - P.y, dz = qp.z - P.z;
            const float d = fmaf(dx, dx, fmaf(dy, dy, dz * dz));
            unsigned key = (__float_as_uint(d) & 0xFFFFFF00u) | (unsigned)cand;
            key = (cand == p) ? 0xFFFFFFFFu : key;
            INSERTK(key);
        }

        if (half == 1) {
#pragma unroll
            for (int i = 0; i < KNN; ++i) sk[qt][i] = bk[i];
        }
        __syncthreads();
        if (half == 0) {
            for (int j = 0; j < KNN; ++j) {
                const unsigned key = sk[qt][j];
                if (key >= bk[KNN - 1]) break;
                INSERTK(key);
            }
            int* op = knn_out + ((size_t)bb * NP + p) * KNN;
#pragma unroll
            for (int i = 0; i < KNN; ++i) op[i] = (int)(bk[i] & 0xFFu);
        }
    }
}

// ---------------------------------------------------------------------------
// Edge MLP v14: MIXED orientation. L1/L2 register-chained (new orientation,
// verified R17), L3 flipped to OLD orientation by reinterpreting the L2
// packrelu output as an A-frag (same bytes: A[i][h*8+j] = y[h*8+j][i]).
// D3 rows = neighbors -> k-mean = 4 local relu-adds + 2 shfl_xor per tile
// (28 VALU ops vs the 128-op DPP butterfly that dominated R15-R21).
// Weights+biases in registers; no main-loop fences; 4 indep waves/WG.
// ---------------------------------------------------------------------------
__global__ __launch_bounds__(256) void edge_kernel(
    const unsigned short* __restrict__ fbf, const int* __restrict__ knn_idx,
    const unsigned short* __restrict__ wsf, const float* __restrict__ bnp,
    float* __restrict__ out)
{
    __shared__ __align__(16) float s0buf[4][8][64];   // 8 KB
    __shared__ __align__(16) float ftsbuf[4][8][64];  // 8 KB

    const int tid = threadIdx.x;
    const int wid = tid >> 6;
    const int l = tid & 63;
    const int i = l & 15;
    const int h = l >> 4;
    // bijective XCD swizzle: 1024 blocks = 8 XCDs x 128 contiguous work items
    const int wg = (blockIdx.x & 7) * 128 + (blockIdx.x >> 3);
    const int p0 = (wg * 4 + wid) * 8;
    const int b = p0 >> 8;

    // weight frags in registers: 0..7 w0hi(A), 8..15 w1'(A), 16..23 w2'(B-old)
    bf16x8 wr[24];
    {
        const bf16x8* __restrict__ W = (const bf16x8*)(wsf + 4096);
#pragma unroll
        for (int f = 0; f < 24; ++f) wr[f] = W[f * 64 + l];
    }
    // L2 bias (kappa-pos, C-in rows); L3 bias (plain channel, per-column)
    f32x4 cin2[4];
    float c3b[4];
#pragma unroll
    for (int t = 0; t < 4; ++t) {
        cin2[t] = *(const f32x4*)&bnp[64 + t * 16 + 4 * h];
        c3b[t] = bnp[128 + t * 16 + i];
    }

    // ---- prologue: s0 = shf1' + V @ ctr  (new orientation) ----
    bf16x8 a0, a1;   // center B/A-frags (reused by s0 and shortcut)
    {
        const unsigned short* cp = fbf + (size_t)(p0 + (i & 7)) * NC;
        a0 = *(const bf16x8*)(cp + 8 * h);
        a1 = *(const bf16x8*)(cp + 32 + 8 * h);
        const bf16x8* __restrict__ WV = (const bf16x8*)(wsf);
#pragma unroll
        for (int t = 0; t < 4; ++t) {
            f32x4 acc = *(const f32x4*)&bnp[t * 16 + 4 * h];   // shf1'
            acc = mfma16(WV[t * 64 + l], a0, acc);
            acc = mfma16(WV[(4 + t) * 64 + l], a1, acc);
            if (i < 8)
                *(f32x4*)&s0buf[wid][i][t * 16 + 4 * h] = acc;  // col=i=point
        }
    }
    int nks[8];
#pragma unroll
    for (int q = 0; q < 8; ++q) nks[q] = knn_idx[(size_t)(p0 + q) * KNN + i];
    CFENCE();   // s0buf writes before main-loop reads (wave-private)

    // prime point 0's neighbor fragments (lane i -> neighbor i)
    bf16x8 fb0, fb1;
    {
        const unsigned short* sp = fbf + (size_t)(b * NP + nks[0]) * NC;
        fb0 = *(const bf16x8*)(sp + 8 * h);
        fb1 = *(const bf16x8*)(sp + 32 + 8 * h);
    }

#pragma unroll
    for (int q = 0; q < 8; ++q) {
        f32x4 acc[4];
        // ---- L1 (new orient): acc = s0 + W1 . nbr ----
#pragma unroll
        for (int t = 0; t < 4; ++t) {
            f32x4 z = *(const f32x4*)&s0buf[wid][q][t * 16 + 4 * h];
            z = mfma16(wr[t], fb0, z);
            acc[t] = mfma16(wr[4 + t], fb1, z);
        }
        bf16x8 g0, g1;
        if (q < 7) {
            const unsigned short* sp = fbf + (size_t)(b * NP + nks[(q + 1) & 7]) * NC;
            g0 = *(const bf16x8*)(sp + 8 * h);
            g1 = *(const bf16x8*)(sp + 32 + 8 * h);
        }
        bf16x8 x0 = packrelu(acc[0], acc[1]);
        bf16x8 x1 = packrelu(acc[2], acc[3]);

        // ---- L2 (new orient) ----
#pragma unroll
        for (int t = 0; t < 4; ++t) {
            f32x4 z = mfma16(wr[8 + t], x0, cin2[t]);
            acc[t] = mfma16(wr[12 + t], x1, z);
        }
        bf16x8 y0 = packrelu(acc[0], acc[1]);
        bf16x8 y1 = packrelu(acc[2], acc[3]);

        // ---- L3 (OLD orient): y as A-operand, W3 B-frags ----
        // D3[m=neighbor][n=t*16+i]; bias = shf3'[n] splat into C-in.
#pragma unroll
        for (int t = 0; t < 4; ++t) {
            f32x4 z = {c3b[t], c3b[t], c3b[t], c3b[t]};
            z = mfma16(y0, wr[16 + t], z);
            acc[t] = mfma16(y1, wr[20 + t], z);
        }
        // k-mean: 4 local relu-adds + 2 shuffles per tile
#pragma unroll
        for (int t = 0; t < 4; ++t) {
            float s = fmaxf(acc[t][0], 0.f) + fmaxf(acc[t][1], 0.f)
                    + fmaxf(acc[t][2], 0.f) + fmaxf(acc[t][3], 0.f);
            s += __shfl_xor(s, 16, 64);
            s += __shfl_xor(s, 32, 64);
            if (h == 0) ftsbuf[wid][q][t * 16 + i] = s;   // raw sum (scl3/16 later)
        }
        fb0 = g0; fb1 = g1;
    }
    CFENCE();  // ftsbuf writes before epilogue reads (same wave)

    // ---- shortcut GEMM + epilogue (old orientation, plain columns) ----
    {
        const bf16x8* __restrict__ WS = (const bf16x8*)(wsf + 16384);
        float sscl[4], sshf[4], f3[4];
#pragma unroll
        for (int t = 0; t < 4; ++t) {
            sscl[t] = bnp[256 + t * 16 + i];
            sshf[t] = bnp[320 + t * 16 + i];
            f3[t]   = bnp[192 + t * 16 + i];
        }
        f32x4 acc[4];
#pragma unroll
        for (int t = 0; t < 4; ++t) {
            f32x4 z = {0.f, 0.f, 0.f, 0.f};
            z = mfma16(a0, WS[t * 64 + l], z);
            acc[t] = mfma16(a1, WS[(4 + t) * 64 + l], z);
        }
        if (h < 2) {
#pragma unroll
            for (int r = 0; r < 4; ++r) {
                const int q = h * 4 + r;
                float* op = out + (size_t)(p0 + q) * NC;
#pragma unroll
                for (int t = 0; t < 4; ++t) {
                    float fts = ftsbuf[wid][q][t * 16 + i];
                    op[t * 16 + i] = fmaxf(fmaf(acc[t][r], sscl[t], sshf[t]) + fts * f3[t], 0.f);
                }
            }
        }
    }
}

extern "C" void kernel_launch(void* const* d_in, const int* in_sizes, int n_in,
                              void* d_out, int out_size, void* d_ws, size_t ws_size,
                              hipStream_t stream) {
    const float* points    = (const float*)d_in[0];
    const float* features  = (const float*)d_in[1];
    const float* w0        = (const float*)d_in[2];
    const float* w1        = (const float*)d_in[3];
    const float* w2        = (const float*)d_in[4];
    const float* gammas    = (const float*)d_in[5];
    const float* betas     = (const float*)d_in[6];
    const float* means     = (const float*)d_in[7];
    const float* variances = (const float*)d_in[8];
    const float* sc_w      = (const float*)d_in[9];
    const float* sc_gamma  = (const float*)d_in[10];
    const float* sc_beta   = (const float*)d_in[11];
    const float* sc_mean   = (const float*)d_in[12];
    const float* sc_var    = (const float*)d_in[13];
    float* out = (float*)d_out;

    int* knn_buf = (int*)d_ws;                                          // 2 MB
    unsigned short* fbf = (unsigned short*)((char*)d_ws + (1 << 21));   // 4 MB
    unsigned short* wsf = (unsigned short*)((char*)d_ws + (3 << 21));   // 40 KB
    float* bnp = (float*)((char*)d_ws + (3 << 21) + 40960);             // 1.5 KB

    setup_kernel<<<1362, 256, 0, stream>>>(points, features, w0, w1, w2, sc_w,
                                           gammas, betas, means, variances,
                                           sc_gamma, sc_beta, sc_mean, sc_var,
                                           fbf, wsf, bnp, knn_buf);
    edge_kernel<<<NBATCH * NP / 32, 256, 0, stream>>>(fbf, knn_buf, wsf, bnp, out);
}